// Round 1
// baseline (1028.029 us; speedup 1.0000x reference)
//
#include <hip/hip_runtime.h>
#include <cstdint>
#include <cstddef>

typedef __bf16 bf16;
typedef float f32x4 __attribute__((ext_vector_type(4)));
typedef bf16  bf16x4 __attribute__((ext_vector_type(4)));
typedef bf16  bf16x8 __attribute__((ext_vector_type(8)));

#define DIMD   2048
#define HEADS  32
#define DH     64
#define FFI    8192
#define FUSEDN 18560
#define BB     2
#define NN     2048
#define MROWS  4096   // BB*NN
#define K2     10240  // DIMD + FFI

// async global->LDS, 16B per lane, wave-uniform LDS base
__device__ __forceinline__ void gl_lds16(const void* g, void* l) {
  __builtin_amdgcn_global_load_lds(
      (__attribute__((address_space(1))) void*)const_cast<void*>(g),
      (__attribute__((address_space(3))) void*)l, 16, 0, 0);
}

// ---------------- fp32 -> bf16 conversion (optionally strided dst) ----------------
__global__ void k_cvt_str(const float* __restrict__ s, bf16* __restrict__ d,
                          long total4, int cols, int dstride, int doff) {
  long stride = (long)gridDim.x * blockDim.x;
  for (long i = (long)blockIdx.x * blockDim.x + threadIdx.x; i < total4; i += stride) {
    long e = i << 2;
    long r = e / cols;
    int  c = (int)(e - r * (long)cols);
    float4 v = *(const float4*)(s + e);
    bf16x4 o; o[0]=(bf16)v.x; o[1]=(bf16)v.y; o[2]=(bf16)v.z; o[3]=(bf16)v.w;
    *(bf16x4*)(d + r * (long)dstride + doff + c) = o;
  }
}

// ---------------- LayerNorm (per row) -> bf16 ----------------
__global__ __launch_bounds__(256) void k_ln(const float* __restrict__ x,
                                            const float* __restrict__ g,
                                            bf16* __restrict__ xn) {
  int row = blockIdx.x, t = threadIdx.x;
  const float4* xr = (const float4*)(x + (size_t)row * DIMD);
  float4 a = xr[t*2], b = xr[t*2+1];
  float s  = a.x+a.y+a.z+a.w + b.x+b.y+b.z+b.w;
  float s2 = a.x*a.x+a.y*a.y+a.z*a.z+a.w*a.w + b.x*b.x+b.y*b.y+b.z*b.z+b.w*b.w;
  for (int o = 1; o < 64; o <<= 1) { s += __shfl_xor(s, o); s2 += __shfl_xor(s2, o); }
  __shared__ float rs[8];
  if ((t & 63) == 0) { rs[t>>6] = s; rs[4 + (t>>6)] = s2; }
  __syncthreads();
  s = rs[0]+rs[1]+rs[2]+rs[3]; s2 = rs[4]+rs[5]+rs[6]+rs[7];
  float mu = s * (1.f/DIMD);
  float var = s2 * (1.f/DIMD) - mu*mu;
  float rstd = rsqrtf(var + 1e-5f);
  const float4* gr = (const float4*)g;
  float4 g0 = gr[t*2], g1 = gr[t*2+1];
  bf16x8 o;
  o[0]=(bf16)((a.x-mu)*rstd*g0.x); o[1]=(bf16)((a.y-mu)*rstd*g0.y);
  o[2]=(bf16)((a.z-mu)*rstd*g0.z); o[3]=(bf16)((a.w-mu)*rstd*g0.w);
  o[4]=(bf16)((b.x-mu)*rstd*g1.x); o[5]=(bf16)((b.y-mu)*rstd*g1.y);
  o[6]=(bf16)((b.z-mu)*rstd*g1.z); o[7]=(bf16)((b.w-mu)*rstd*g1.w);
  *(bf16x8*)(xn + (size_t)row * DIMD + t*8) = o;
}

// ---------------- GEMM1: proj = xn(4096x2048) @ Wf^T(2048x18560), routed epilogue ----------------
__global__ __launch_bounds__(256) void k_gemm1(const bf16* __restrict__ xn,
                                               const bf16* __restrict__ wf,
                                               bf16* __restrict__ q_raw,
                                               bf16* __restrict__ k_buf,
                                               bf16* __restrict__ v_t,
                                               bf16* __restrict__ proj_ff) {
  __shared__ bf16 At[128*32];
  __shared__ bf16 Bt[128*32];
  const int tid = threadIdx.x, w = tid >> 6, l = tid & 63;
  const int l15 = l & 15, h4 = l >> 4;
  const int nt = blockIdx.x, mt = blockIdx.y;
  const int m0 = mt * 128, f0 = nt * 128;
  const int wr = w >> 1, wc = w & 1;
  const bf16* Ab = xn + (size_t)m0 * DIMD;
  const bf16* Bb = wf + (size_t)f0 * DIMD;
  f32x4 zf = {0.f,0.f,0.f,0.f};
  f32x4 acc[4][4];
#pragma unroll
  for (int i = 0; i < 4; i++)
#pragma unroll
    for (int j = 0; j < 4; j++) acc[i][j] = zf;

  for (int k0 = 0; k0 < DIMD; k0 += 32) {
#pragma unroll
    for (int c = 0; c < 2; c++) {
      int chunk = c*256 + tid;
      int r = chunk >> 2, c8 = (chunk & 3) << 3;
      gl_lds16(Ab + (size_t)r * DIMD + k0 + c8, At + ((size_t)(chunk & ~63) << 3));
      gl_lds16(Bb + (size_t)r * DIMD + k0 + c8, Bt + ((size_t)(chunk & ~63) << 3));
    }
    __syncthreads();
    bf16x8 af[4], bfr[4];
#pragma unroll
    for (int i = 0; i < 4; i++) af[i]  = *(const bf16x8*)(At + (wr*64 + i*16 + l15)*32 + h4*8);
#pragma unroll
    for (int i = 0; i < 4; i++) bfr[i] = *(const bf16x8*)(Bt + (wc*64 + i*16 + l15)*32 + h4*8);
#pragma unroll
    for (int i = 0; i < 4; i++)
#pragma unroll
      for (int j = 0; j < 4; j++)
        acc[i][j] = __builtin_amdgcn_mfma_f32_16x16x32_bf16(af[i], bfr[j], acc[i][j], 0, 0, 0);
    __syncthreads();
  }
#pragma unroll
  for (int i = 0; i < 4; i++)
#pragma unroll
    for (int jn = 0; jn < 4; jn++) {
      int fcol = f0 + wc*64 + jn*16 + l15;
#pragma unroll
      for (int j = 0; j < 4; j++) {
        int m = m0 + wr*64 + i*16 + h4*4 + j;
        bf16 bv = (bf16)acc[i][jn][j];
        int b = m >> 11, n = m & 2047;
        if (fcol < 2048) {
          int hh = fcol >> 6, d = fcol & 63;
          q_raw[(((size_t)(b*HEADS + hh) * NN + n) << 6) + d] = bv;
        } else if (fcol < 2112) {
          k_buf[(((size_t)(b*NN + n)) << 6) + (fcol - 2048)] = bv;
        } else if (fcol < 2176) {
          v_t[(((size_t)(b*DH + (fcol - 2112))) << 11) + n] = bv;
        } else {
          proj_ff[((size_t)m << 14) + (fcol - 2176)] = bv;
        }
      }
    }
}

// ---------------- RoPE in-place on q_raw (with 1/8 fold) and k_buf (inverse scale) ----------------
__global__ void k_rope(bf16* __restrict__ q_raw, bf16* __restrict__ k_buf) {
  const long QT = (long)BB*HEADS*NN*32;
  const long TOT = QT + (long)BB*NN*32;
  long gid = (long)blockIdx.x * blockDim.x + threadIdx.x;
  if (gid >= TOT) return;
  bool isq = gid < QT;
  long idx = isq ? gid : gid - QT;
  int  i = (int)(idx & 31);
  long row = idx >> 5;
  int  n = (int)(row & (NN - 1));
  bf16* base = (isq ? q_raw : k_buf) + row * DH;
  float t1 = (float)base[i];
  float t2 = (float)base[i + 32];
  float inv_freq = __powf(10000.f, -(float)i * (1.f/32.f));
  float th = (float)n * inv_freq;
  float sn, cs;
  __sincosf(th, &sn, &cs);
  float power = ((float)n - (float)(NN/2)) * (1.f/512.f);
  float sb = ((float)(2*i) + 25.6f) * (1.f/89.6f);
  float sc = __powf(sb, isq ? power : -power);
  float mm = isq ? 0.125f : 1.0f;
  float o1 = (t1*cs - t2*sn) * sc * mm;
  float o2 = (t2*cs + t1*sn) * sc * mm;
  base[i]      = (bf16)o1;
  base[i + 32] = (bf16)o2;
}

// ---------------- causal MQA flash attention ----------------
// blocks: ((b*HEADS+h)<<4) | qt ; 4 waves, each owns 32 q rows; KV tiles of 32
__global__ __launch_bounds__(256) void k_attn(const bf16* __restrict__ qbuf,
                                              const bf16* __restrict__ kbuf,
                                              const bf16* __restrict__ vtb,
                                              bf16* __restrict__ uo) {
  __shared__ bf16 Qs[128*64];  // swizzled rows (128B rows, XOR 16*(r&7))
  __shared__ bf16 Ks[32*64];
  __shared__ bf16 Vs[64*32];   // V^T tile, XOR 16*(d&3)
  const int tid = threadIdx.x, w = tid >> 6, l = tid & 63;
  const int l15 = l & 15, h4 = l >> 4;
  const int bid = blockIdx.x;
  const int qt = bid & 15, bh = bid >> 4;
  const int h = bh & (HEADS - 1), b = bh >> 5;
  const int q0 = qt * 128;
  const bf16* Qg = qbuf + ((size_t)(b*HEADS + h) * NN + q0) * DH;
  const bf16* Kg = kbuf + (size_t)b * NN * DH;
  const bf16* Vg = vtb + (size_t)b * DH * NN;

#pragma unroll
  for (int c = 0; c < 4; c++) {
    int chunk = c*256 + tid;
    int r = chunk >> 3, cc = chunk & 7;
    int col8 = (cc ^ (r & 7)) << 3;
    gl_lds16(Qg + (size_t)r*DH + col8, Qs + ((size_t)(chunk & ~63) << 3));
  }
  __syncthreads();

  const int wq0 = q0 + w*32;
  bf16x8 qfr[2][2];
#pragma unroll
  for (int qf = 0; qf < 2; qf++)
#pragma unroll
    for (int c = 0; c < 2; c++) {
      int row = w*32 + qf*16 + l15;
      int x = (64*c + 16*h4) ^ (16*(row & 7));
      qfr[qf][c] = *(const bf16x8*)((const char*)Qs + row*128 + x);
    }

  f32x4 zf = {0.f,0.f,0.f,0.f};
  f32x4 o_[2][4];
#pragma unroll
  for (int qf = 0; qf < 2; qf++)
#pragma unroll
    for (int nf = 0; nf < 4; nf++) o_[qf][nf] = zf;
  float mrun[2] = {-3e38f, -3e38f};
  float lrun[2] = {0.f, 0.f};

  const int nsteps = (q0 + 128) >> 5;
  for (int kt = 0; kt < nsteps; kt++) {
    const int kv0 = kt << 5;
    {
      int r = tid >> 3, cc = tid & 7;
      int col8 = (cc ^ (r & 7)) << 3;
      gl_lds16(Kg + (size_t)(kv0 + r)*DH + col8, Ks + ((size_t)(tid & ~63) << 3));
    }
    {
      int d = tid >> 2, cc = tid & 3;
      int col8 = (cc ^ (d & 3)) << 3;
      gl_lds16(Vg + (size_t)d*NN + kv0 + col8, Vs + ((size_t)(tid & ~63) << 3));
    }
    __syncthreads();
    if (kv0 <= wq0 + 31) {
      bf16x8 ka[2][2];
#pragma unroll
      for (int kvf = 0; kvf < 2; kvf++)
#pragma unroll
        for (int c = 0; c < 2; c++) {
          int r = kvf*16 + l15;
          int x = (64*c + 16*h4) ^ (16*(r & 7));
          ka[kvf][c] = *(const bf16x8*)((const char*)Ks + r*128 + x);
        }
      // S^T = K · Q^T  (C cols = q, so P is directly A-fragment oriented)
      f32x4 st[2][2];
#pragma unroll
      for (int kvf = 0; kvf < 2; kvf++)
#pragma unroll
        for (int qf = 0; qf < 2; qf++) {
          f32x4 s = __builtin_amdgcn_mfma_f32_16x16x32_bf16(ka[kvf][0], qfr[qf][0], zf, 0, 0, 0);
          s = __builtin_amdgcn_mfma_f32_16x16x32_bf16(ka[kvf][1], qfr[qf][1], s, 0, 0, 0);
          st[kvf][qf] = s;
        }
      if (kv0 + 31 > wq0) {
#pragma unroll
        for (int kvf = 0; kvf < 2; kvf++)
#pragma unroll
          for (int j = 0; j < 4; j++) {
            int kvg = kv0 + kvf*16 + h4*4 + j;
#pragma unroll
            for (int qf = 0; qf < 2; qf++) {
              int qg = wq0 + qf*16 + l15;
              if (kvg > qg) st[kvf][qf][j] = -3e38f;
            }
          }
      }
      bf16x8 pa[2];
#pragma unroll
      for (int qf = 0; qf < 2; qf++) {
        float vmax = -3e38f;
#pragma unroll
        for (int kvf = 0; kvf < 2; kvf++)
#pragma unroll
          for (int j = 0; j < 4; j++) vmax = fmaxf(vmax, st[kvf][qf][j]);
        vmax = fmaxf(vmax, __shfl_xor(vmax, 16));
        vmax = fmaxf(vmax, __shfl_xor(vmax, 32));
        float mnew = fmaxf(mrun[qf], vmax);
        float corr = __expf(mrun[qf] - mnew);
        float ps = 0.f;
        float pv_[8];
#pragma unroll
        for (int kvf = 0; kvf < 2; kvf++)
#pragma unroll
          for (int j = 0; j < 4; j++) {
            float p = __expf(st[kvf][qf][j] - mnew);
            pv_[kvf*4 + j] = p; ps += p;
          }
        ps += __shfl_xor(ps, 16);
        ps += __shfl_xor(ps, 32);
        lrun[qf] = lrun[qf]*corr + ps;
        mrun[qf] = mnew;
        bf16x8 t;
#pragma unroll
        for (int i = 0; i < 8; i++) t[i] = (bf16)pv_[i];
        pa[qf] = t;
#pragma unroll
        for (int j = 0; j < 4; j++) {
          float cj = __shfl(corr, (l & 48) | (h4*4 + j), 64);
#pragma unroll
          for (int nf = 0; nf < 4; nf++) o_[qf][nf][j] *= cj;
        }
      }
      // PV: A=P (k-map g(h,i)=4h+(i&3)+16(i>>2)), B=V with matching g
#pragma unroll
      for (int nf = 0; nf < 4; nf++) {
        int d_ = nf*16 + l15;
        int swz = 16*(d_ & 3);
        const char* vrow = (const char*)Vs + d_*64;
        bf16x4 v0 = *(const bf16x4*)(vrow + ((8*h4) ^ swz));
        bf16x4 v1 = *(const bf16x4*)(vrow + ((8*h4 + 32) ^ swz));
        bf16x8 vb = __builtin_shufflevector(v0, v1, 0,1,2,3,4,5,6,7);
#pragma unroll
        for (int qf = 0; qf < 2; qf++)
          o_[qf][nf] = __builtin_amdgcn_mfma_f32_16x16x32_bf16(pa[qf], vb, o_[qf][nf], 0, 0, 0);
      }
    }
    __syncthreads();
  }
#pragma unroll
  for (int qf = 0; qf < 2; qf++) {
    float inv = 1.f / lrun[qf];
#pragma unroll
    for (int j = 0; j < 4; j++) {
      float ij = __shfl(inv, (l & 48) | (h4*4 + j), 64);
      int qg = wq0 + qf*16 + h4*4 + j;
      size_t rowoff = (size_t)(b*NN + qg) * DIMD + h*DH;
#pragma unroll
      for (int nf = 0; nf < 4; nf++)
        uo[rowoff + nf*16 + l15] = (bf16)(o_[qf][nf][j] * ij);
    }
  }
}

// ---------------- SiLU gating, in-place over ff_x half of proj_ff ----------------
__global__ void k_silu(bf16* __restrict__ pf) {
  const long total4 = (long)MROWS * FFI / 4;
  long stride = (long)gridDim.x * blockDim.x;
  for (long i = (long)blockIdx.x * blockDim.x + threadIdx.x; i < total4; i += stride) {
    long e = i << 2;
    long m = e >> 13;          // /FFI
    int  c = (int)(e & (FFI - 1));
    bf16* px = pf + (m << 14) + c;
    bf16x4 fx = *(const bf16x4*)px;
    bf16x4 gt = *(const bf16x4*)(px + FFI);
    bf16x4 r;
#pragma unroll
    for (int k = 0; k < 4; k++) {
      float g = (float)gt[k], f = (float)fx[k];
      float s = g * (1.f / (1.f + __expf(-g)));
      r[k] = (bf16)(s * f);
    }
    *(bf16x4*)px = r;
  }
}

// ---------------- GEMM2: out = [O | ffh](4096x10240) @ Wcat^T -> fp32 d_out ----------------
__global__ __launch_bounds__(256) void k_gemm2(const bf16* __restrict__ u_o,
                                               const bf16* __restrict__ ffh,
                                               const bf16* __restrict__ wcat,
                                               float* __restrict__ out) {
  __shared__ bf16 At[128*32];
  __shared__ bf16 Bt[128*32];
  const int tid = threadIdx.x, w = tid >> 6, l = tid & 63;
  const int l15 = l & 15, h4 = l >> 4;
  const int nt = blockIdx.x, mt = blockIdx.y;
  const int m0 = mt * 128, f0 = nt * 128;
  const int wr = w >> 1, wc = w & 1;
  f32x4 zf = {0.f,0.f,0.f,0.f};
  f32x4 acc[4][4];
#pragma unroll
  for (int i = 0; i < 4; i++)
#pragma unroll
    for (int j = 0; j < 4; j++) acc[i][j] = zf;

  for (int k0 = 0; k0 < K2; k0 += 32) {
    const bf16* Ag; size_t lda;
    if (k0 < DIMD) { Ag = u_o + (size_t)m0*DIMD + k0;              lda = DIMD; }
    else           { Ag = ffh + (size_t)m0*16384 + (k0 - DIMD);    lda = 16384; }
#pragma unroll
    for (int c = 0; c < 2; c++) {
      int chunk = c*256 + tid;
      int r = chunk >> 2, c8 = (chunk & 3) << 3;
      gl_lds16(Ag + (size_t)r*lda + c8, At + ((size_t)(chunk & ~63) << 3));
      gl_lds16(wcat + (size_t)(f0 + r)*K2 + k0 + c8, Bt + ((size_t)(chunk & ~63) << 3));
    }
    __syncthreads();
    bf16x8 af[4], bfr[4];
#pragma unroll
    for (int i = 0; i < 4; i++) af[i]  = *(const bf16x8*)(At + (wr*64 + i*16 + l15)*32 + h4*8);
#pragma unroll
    for (int i = 0; i < 4; i++) bfr[i] = *(const bf16x8*)(Bt + (wc*64 + i*16 + l15)*32 + h4*8);
#pragma unroll
    for (int i = 0; i < 4; i++)
#pragma unroll
      for (int j = 0; j < 4; j++)
        acc[i][j] = __builtin_amdgcn_mfma_f32_16x16x32_bf16(af[i], bfr[j], acc[i][j], 0, 0, 0);
    __syncthreads();
  }
#pragma unroll
  for (int i = 0; i < 4; i++)
#pragma unroll
    for (int jn = 0; jn < 4; jn++) {
      int fcol = f0 + wc*64 + jn*16 + l15;
#pragma unroll
      for (int j = 0; j < 4; j++) {
        int m = m0 + wr*64 + i*16 + h4*4 + j;
        out[(size_t)m*DIMD + fcol] = acc[i][jn][j];
      }
    }
}

extern "C" void kernel_launch(void* const* d_in, const int* in_sizes, int n_in,
                              void* d_out, int out_size, void* d_ws, size_t ws_size,
                              hipStream_t stream) {
  const float* x     = (const float*)d_in[0];
  const float* gamma = (const float*)d_in[1];
  const float* Wf    = (const float*)d_in[2];
  const float* Wao   = (const float*)d_in[3];
  const float* Wff   = (const float*)d_in[4];
  float* out = (float*)d_out;
  char* ws = (char*)d_ws;

  size_t o = 0;
  bf16* wfb     = (bf16*)(ws + o); o += (size_t)FUSEDN * DIMD * 2;   // 76.0 MB
  bf16* wcat    = wfb;                                               // aliased (used after GEMM1)
  bf16* xn      = (bf16*)(ws + o); o += (size_t)MROWS * DIMD * 2;    // 16.8 MB
  bf16* q_raw   = (bf16*)(ws + o); o += (size_t)BB*HEADS*NN*DH * 2;  // 16.8 MB
  bf16* k_buf   = (bf16*)(ws + o); o += (size_t)BB*NN*DH * 2;        // 0.5 MB
  bf16* v_t     = (bf16*)(ws + o); o += (size_t)BB*DH*NN * 2;        // 0.5 MB
  bf16* proj_ff = (bf16*)(ws + o); o += (size_t)MROWS * 2*FFI * 2;   // 134.2 MB
  bf16* u_o     = (bf16*)(ws + o); o += (size_t)MROWS * DIMD * 2;    // 16.8 MB  (total ~262 MB)

  // 1. W_fused -> bf16
  k_cvt_str<<<2048, 256, 0, stream>>>(Wf, wfb, (long)FUSEDN*DIMD/4, DIMD, DIMD, 0);
  // 2. LayerNorm
  k_ln<<<MROWS, 256, 0, stream>>>(x, gamma, xn);
  // 3. fused projection GEMM
  k_gemm1<<<dim3(FUSEDN/128, MROWS/128), 256, 0, stream>>>(xn, wfb, q_raw, k_buf, v_t, proj_ff);
  // 4. Wcat = [Wao | Wff] -> bf16 (over wfb region; stream-ordered after GEMM1)
  k_cvt_str<<<512,  256, 0, stream>>>(Wao, wcat, (long)DIMD*DIMD/4, DIMD, K2, 0);
  k_cvt_str<<<1024, 256, 0, stream>>>(Wff, wcat, (long)DIMD*FFI/4,  FFI,  K2, DIMD);
  // 5. RoPE (q with scale & 1/8, k with inverse scale), in place
  {
    long tot = (long)BB*HEADS*NN*32 + (long)BB*NN*32;
    k_rope<<<(int)((tot + 255) / 256), 256, 0, stream>>>(q_raw, k_buf);
  }
  // 6. flash attention -> u_o
  k_attn<<<BB*HEADS*(NN/128), 256, 0, stream>>>(q_raw, k_buf, v_t, u_o);
  // 7. SiLU gate in place (ff_hidden into first half of proj_ff rows)
  k_silu<<<2048, 256, 0, stream>>>(proj_ff);
  // 8. combined output GEMM -> d_out (fp32)
  k_gemm2<<<dim3(DIMD/128, MROWS/128), 256, 0, stream>>>(u_o, proj_ff, wcat, out);
}

// Round 2
// 927.073 us; speedup vs baseline: 1.1089x; 1.1089x over previous
//
#include <hip/hip_runtime.h>
#include <cstdint>
#include <cstddef>

typedef __bf16 bf16;
typedef float f32x4 __attribute__((ext_vector_type(4)));
typedef bf16  bf16x4 __attribute__((ext_vector_type(4)));
typedef bf16  bf16x8 __attribute__((ext_vector_type(8)));

#define DIMD   2048
#define HEADS  32
#define DH     64
#define FFI    8192
#define FUSEDN 18560
#define FUSEDP 18688   // padded to 73*256
#define BB     2
#define NN     2048
#define MROWS  4096   // BB*NN
#define K2     10240  // DIMD + FFI

// async global->LDS, 16B per lane, wave-uniform LDS base
__device__ __forceinline__ void gl_lds16(const void* g, void* l) {
  __builtin_amdgcn_global_load_lds(
      (__attribute__((address_space(1))) void*)const_cast<void*>(g),
      (__attribute__((address_space(3))) void*)l, 16, 0, 0);
}

struct SrcT { const bf16* g; long ldk; };

// Stage one 512-chunk (8KB) instruction of a [rows][64] bf16 K-tile into LDS.
// LDS dest is linear (global_load_lds constraint); the T2 swizzle is applied
// on the GLOBAL source: LDS chunk (row, c) receives global chunk (row, c^(row&7)).
__device__ __forceinline__ void stage_instr(const bf16* g, long ldk,
                                            bf16* region, int instr, int tid) {
  int L = instr * 512 + tid;
  int row = L >> 3, c = L & 7;
  int cs = c ^ (row & 7);
  gl_lds16(g + (size_t)row * ldk + cs * 8,
           region + (size_t)(instr * 512 + (tid & ~63)) * 8);
}

// Swizzled fragment read: logical (row, k=ks*32+h4*8..+7)
__device__ __forceinline__ bf16x8 frag_ld(const bf16* region, int row, int ks, int h4) {
  int cs = (ks * 4 + h4) ^ (row & 7);
  return *(const bf16x8*)(region + (size_t)row * 64 + cs * 8);
}

// ---- 8-phase double-buffered GEMM core (BM = MFR*32, BN = 256, BK = 64) ----
template <int MFR, typename FA, typename FB>
__device__ __forceinline__ void gemm_core(FA fa, FB fb, const int NT,
    bf16* AsB, bf16* BsB, f32x4 (&acc)[MFR][4],
    const int tid, const int wrow, const int nbase, const int l15, const int h4)
{
  constexpr int ASZ = MFR * 32 * 64;
  constexpr int BSZ = 256 * 64;
  constexpr int AIN = MFR / 2;   // global_load_lds instructions per A tile
  bf16x8 af[MFR], b0, b1;

#define STAGE_A(t) do { SrcT s_ = fa(t); _Pragma("unroll") \
    for (int q_ = 0; q_ < AIN; q_++) stage_instr(s_.g, s_.ldk, AsB + ((t)&1)*ASZ, q_, tid); } while(0)
#define STAGE_B(t) do { SrcT s_ = fb(t); _Pragma("unroll") \
    for (int q_ = 0; q_ < 4; q_++) stage_instr(s_.g, s_.ldk, BsB + ((t)&1)*BSZ, q_, tid); } while(0)

  // prologue: tile0 (A+B) and tile1's A; drain all but tile1's A loads
  STAGE_A(0); STAGE_B(0); STAGE_A(1);
  asm volatile("s_waitcnt vmcnt(%0)" :: "i"(AIN) : "memory");
  __builtin_amdgcn_s_barrier();

#define PH(bb, ks, nh, STG, WCODE) do {                                       \
    if ((nh) == 0) {                                                          \
      _Pragma("unroll")                                                       \
      for (int m_ = 0; m_ < MFR; m_++)                                        \
        af[m_] = frag_ld(AsB + (bb)*ASZ, wrow + m_*16 + l15, ks, h4);         \
    }                                                                         \
    b0 = frag_ld(BsB + (bb)*BSZ, nbase + ((nh)*2+0)*16 + l15, ks, h4);        \
    b1 = frag_ld(BsB + (bb)*BSZ, nbase + ((nh)*2+1)*16 + l15, ks, h4);        \
    STG;                                                                      \
    __builtin_amdgcn_s_barrier();                                             \
    asm volatile("s_waitcnt lgkmcnt(0)" ::: "memory");                        \
    __builtin_amdgcn_sched_barrier(0);                                        \
    __builtin_amdgcn_s_setprio(1);                                            \
    _Pragma("unroll")                                                         \
    for (int m_ = 0; m_ < MFR; m_++) {                                        \
      acc[m_][(nh)*2+0] = __builtin_amdgcn_mfma_f32_16x16x32_bf16(af[m_], b0, acc[m_][(nh)*2+0], 0,0,0); \
      acc[m_][(nh)*2+1] = __builtin_amdgcn_mfma_f32_16x16x32_bf16(af[m_], b1, acc[m_][(nh)*2+1], 0,0,0); \
    }                                                                         \
    __builtin_amdgcn_s_setprio(0);                                            \
    WCODE;                                                                    \
    __builtin_amdgcn_s_barrier();                                             \
  } while(0)

  for (int it = 0; it < NT / 2; ++it) {
    const int t0 = 2 * it, t1 = t0 + 1;
    // phases 1-4: compute tile t0 (buf0); phases 5-8: tile t1 (buf1)
    PH(0, 0, 0, STAGE_B(t1), (void)0);
    PH(0, 0, 1, (void)0, (void)0);
    PH(0, 1, 0, (void)0, (void)0);
    PH(0, 1, 1,
       if (t0 + 2 < NT) STAGE_A(t0 + 2),
       if (t0 + 2 < NT) { asm volatile("s_waitcnt vmcnt(%0)" :: "i"(AIN) : "memory"); }
       else             { asm volatile("s_waitcnt vmcnt(0)" ::: "memory"); });
    PH(1, 0, 0, if (t0 + 2 < NT) STAGE_B(t0 + 2), (void)0);
    PH(1, 0, 1, (void)0, (void)0);
    PH(1, 1, 0, (void)0, (void)0);
    PH(1, 1, 1,
       if (t1 + 2 < NT) STAGE_A(t1 + 2),
       if (t1 + 2 < NT) { asm volatile("s_waitcnt vmcnt(%0)" :: "i"(AIN) : "memory"); }
       else             { asm volatile("s_waitcnt vmcnt(0)" ::: "memory"); });
  }
#undef PH
#undef STAGE_A
#undef STAGE_B
}

// ---------------- fp32 -> bf16 conversion (optionally strided dst) ----------------
__global__ void k_cvt_str(const float* __restrict__ s, bf16* __restrict__ d,
                          long total4, int cols, int dstride, int doff) {
  long stride = (long)gridDim.x * blockDim.x;
  for (long i = (long)blockIdx.x * blockDim.x + threadIdx.x; i < total4; i += stride) {
    long e = i << 2;
    long r = e / cols;
    int  c = (int)(e - r * (long)cols);
    float4 v = *(const float4*)(s + e);
    bf16x4 o; o[0]=(bf16)v.x; o[1]=(bf16)v.y; o[2]=(bf16)v.z; o[3]=(bf16)v.w;
    *(bf16x4*)(d + r * (long)dstride + doff + c) = o;
  }
}

// ---------------- LayerNorm (per row) -> bf16 ----------------
__global__ __launch_bounds__(256) void k_ln(const float* __restrict__ x,
                                            const float* __restrict__ g,
                                            bf16* __restrict__ xn) {
  int row = blockIdx.x, t = threadIdx.x;
  const float4* xr = (const float4*)(x + (size_t)row * DIMD);
  float4 a = xr[t*2], b = xr[t*2+1];
  float s  = a.x+a.y+a.z+a.w + b.x+b.y+b.z+b.w;
  float s2 = a.x*a.x+a.y*a.y+a.z*a.z+a.w*a.w + b.x*b.x+b.y*b.y+b.z*b.z+b.w*b.w;
  for (int o = 1; o < 64; o <<= 1) { s += __shfl_xor(s, o); s2 += __shfl_xor(s2, o); }
  __shared__ float rs[8];
  if ((t & 63) == 0) { rs[t>>6] = s; rs[4 + (t>>6)] = s2; }
  __syncthreads();
  s = rs[0]+rs[1]+rs[2]+rs[3]; s2 = rs[4]+rs[5]+rs[6]+rs[7];
  float mu = s * (1.f/DIMD);
  float var = s2 * (1.f/DIMD) - mu*mu;
  float rstd = rsqrtf(var + 1e-5f);
  const float4* gr = (const float4*)g;
  float4 g0 = gr[t*2], g1 = gr[t*2+1];
  bf16x8 o;
  o[0]=(bf16)((a.x-mu)*rstd*g0.x); o[1]=(bf16)((a.y-mu)*rstd*g0.y);
  o[2]=(bf16)((a.z-mu)*rstd*g0.z); o[3]=(bf16)((a.w-mu)*rstd*g0.w);
  o[4]=(bf16)((b.x-mu)*rstd*g1.x); o[5]=(bf16)((b.y-mu)*rstd*g1.y);
  o[6]=(bf16)((b.z-mu)*rstd*g1.z); o[7]=(bf16)((b.w-mu)*rstd*g1.w);
  *(bf16x8*)(xn + (size_t)row * DIMD + t*8) = o;
}

// ---------------- GEMM1: proj = xn(4096x2048) @ Wf^T, routed epilogue ----------------
__global__ __launch_bounds__(512, 2) void k_gemm1(const bf16* __restrict__ xn,
                                                  const bf16* __restrict__ wf,
                                                  bf16* __restrict__ q_raw,
                                                  bf16* __restrict__ k_buf,
                                                  bf16* __restrict__ v_t,
                                                  bf16* __restrict__ proj_ff) {
  __shared__ bf16 As[2*256*64];
  __shared__ bf16 Bs[2*256*64];
  const int tid = threadIdx.x, w = tid >> 6, l = tid & 63;
  const int l15 = l & 15, h4 = l >> 4;
  const int wr = w >> 2, wc = w & 3;
  const int nwg = gridDim.x, bid = blockIdx.x;
  const int bs = (bid & 7) * (nwg >> 3) + (bid >> 3);   // XCD swizzle (1168 % 8 == 0)
  const int mt = bs & 15, nt = bs >> 4;
  const int m0 = mt * 256, f0 = nt * 256;
  const int wrow = wr * 128, nbase = wc * 64;

  f32x4 acc[8][4];
#pragma unroll
  for (int i = 0; i < 8; i++)
#pragma unroll
    for (int j = 0; j < 4; j++) acc[i][j] = (f32x4){0.f,0.f,0.f,0.f};

  auto fa = [&](int t) -> SrcT { return SrcT{ xn + (size_t)m0 * DIMD + t * 64, (long)DIMD }; };
  auto fb = [&](int t) -> SrcT { return SrcT{ wf + (size_t)f0 * DIMD + t * 64, (long)DIMD }; };
  gemm_core<8>(fa, fb, DIMD / 64, As, Bs, acc, tid, wrow, nbase, l15, h4);

#pragma unroll
  for (int m_ = 0; m_ < 8; m_++)
#pragma unroll
    for (int nf = 0; nf < 4; nf++) {
      int fcol = f0 + nbase + nf*16 + l15;
      if (fcol < FUSEDN) {
#pragma unroll
        for (int j = 0; j < 4; j++) {
          int m = m0 + wrow + m_*16 + h4*4 + j;
          bf16 bv = (bf16)acc[m_][nf][j];
          int b = m >> 11, n = m & 2047;
          if (fcol < 2048) {
            int hh = fcol >> 6, d = fcol & 63;
            q_raw[(((size_t)(b*HEADS + hh) * NN + n) << 6) + d] = bv;
          } else if (fcol < 2112) {
            k_buf[(((size_t)(b*NN + n)) << 6) + (fcol - 2048)] = bv;
          } else if (fcol < 2176) {
            v_t[(((size_t)(b*DH + (fcol - 2112))) << 11) + n] = bv;
          } else {
            proj_ff[((size_t)m << 14) + (fcol - 2176)] = bv;
          }
        }
      }
    }
}

// ---------------- GEMM2: out = [O | ffh](4096x10240) @ Wcat^T -> fp32 ----------------
__global__ __launch_bounds__(512, 2) void k_gemm2(const bf16* __restrict__ u_o,
                                                  const bf16* __restrict__ ffh,
                                                  const bf16* __restrict__ wcat,
                                                  float* __restrict__ out) {
  __shared__ bf16 As[2*128*64];
  __shared__ bf16 Bs[2*256*64];
  const int tid = threadIdx.x, w = tid >> 6, l = tid & 63;
  const int l15 = l & 15, h4 = l >> 4;
  const int wr = w >> 2, wc = w & 3;
  const int bid = blockIdx.x;
  const int bs = (bid & 7) * 32 + (bid >> 3);           // XCD swizzle (256 blocks)
  const int mt = bs & 31, nt = bs >> 5;
  const int m0 = mt * 128, f0 = nt * 256;
  const int wrow = wr * 64, nbase = wc * 64;

  f32x4 acc[4][4];
#pragma unroll
  for (int i = 0; i < 4; i++)
#pragma unroll
    for (int j = 0; j < 4; j++) acc[i][j] = (f32x4){0.f,0.f,0.f,0.f};

  auto fa = [&](int t) -> SrcT {
    int k0 = t * 64;
    if (k0 < DIMD) return SrcT{ u_o + (size_t)m0 * DIMD + k0, (long)DIMD };
    return SrcT{ ffh + (size_t)m0 * 16384 + (k0 - DIMD), (long)16384 };
  };
  auto fb = [&](int t) -> SrcT { return SrcT{ wcat + (size_t)f0 * K2 + t * 64, (long)K2 }; };
  gemm_core<4>(fa, fb, K2 / 64, As, Bs, acc, tid, wrow, nbase, l15, h4);

#pragma unroll
  for (int m_ = 0; m_ < 4; m_++)
#pragma unroll
    for (int nf = 0; nf < 4; nf++) {
      int fcol = f0 + nbase + nf*16 + l15;
#pragma unroll
      for (int j = 0; j < 4; j++) {
        int m = m0 + wrow + m_*16 + h4*4 + j;
        out[(size_t)m * DIMD + fcol] = acc[m_][nf][j];
      }
    }
}

// ---------------- RoPE in-place on q_raw (with 1/8 fold) and k_buf (inverse scale) ----------------
__global__ void k_rope(bf16* __restrict__ q_raw, bf16* __restrict__ k_buf) {
  const long QT = (long)BB*HEADS*NN*32;
  const long TOT = QT + (long)BB*NN*32;
  long gid = (long)blockIdx.x * blockDim.x + threadIdx.x;
  if (gid >= TOT) return;
  bool isq = gid < QT;
  long idx = isq ? gid : gid - QT;
  int  i = (int)(idx & 31);
  long row = idx >> 5;
  int  n = (int)(row & (NN - 1));
  bf16* base = (isq ? q_raw : k_buf) + row * DH;
  float t1 = (float)base[i];
  float t2 = (float)base[i + 32];
  float inv_freq = __powf(10000.f, -(float)i * (1.f/32.f));
  float th = (float)n * inv_freq;
  float sn, cs;
  __sincosf(th, &sn, &cs);
  float power = ((float)n - (float)(NN/2)) * (1.f/512.f);
  float sb = ((float)(2*i) + 25.6f) * (1.f/89.6f);
  float sc = __powf(sb, isq ? power : -power);
  float mm = isq ? 0.125f : 1.0f;
  float o1 = (t1*cs - t2*sn) * sc * mm;
  float o2 = (t2*cs + t1*sn) * sc * mm;
  base[i]      = (bf16)o1;
  base[i + 32] = (bf16)o2;
}

// ---------------- causal MQA flash attention ----------------
__global__ __launch_bounds__(256) void k_attn(const bf16* __restrict__ qbuf,
                                              const bf16* __restrict__ kbuf,
                                              const bf16* __restrict__ vtb,
                                              bf16* __restrict__ uo) {
  __shared__ bf16 Qs[128*64];
  __shared__ bf16 Ks[32*64];
  __shared__ bf16 Vs[64*32];
  const int tid = threadIdx.x, w = tid >> 6, l = tid & 63;
  const int l15 = l & 15, h4 = l >> 4;
  const int bid = blockIdx.x;
  const int qt = bid & 15, bh = bid >> 4;
  const int h = bh & (HEADS - 1), b = bh >> 5;
  const int q0 = qt * 128;
  const bf16* Qg = qbuf + ((size_t)(b*HEADS + h) * NN + q0) * DH;
  const bf16* Kg = kbuf + (size_t)b * NN * DH;
  const bf16* Vg = vtb + (size_t)b * DH * NN;

#pragma unroll
  for (int c = 0; c < 4; c++) {
    int chunk = c*256 + tid;
    int r = chunk >> 3, cc = chunk & 7;
    int col8 = (cc ^ (r & 7)) << 3;
    gl_lds16(Qg + (size_t)r*DH + col8, Qs + ((size_t)(chunk & ~63) << 3));
  }
  __syncthreads();

  const int wq0 = q0 + w*32;
  bf16x8 qfr[2][2];
#pragma unroll
  for (int qf = 0; qf < 2; qf++)
#pragma unroll
    for (int c = 0; c < 2; c++) {
      int row = w*32 + qf*16 + l15;
      int x = (64*c + 16*h4) ^ (16*(row & 7));
      qfr[qf][c] = *(const bf16x8*)((const char*)Qs + row*128 + x);
    }

  f32x4 zf = {0.f,0.f,0.f,0.f};
  f32x4 o_[2][4];
#pragma unroll
  for (int qf = 0; qf < 2; qf++)
#pragma unroll
    for (int nf = 0; nf < 4; nf++) o_[qf][nf] = zf;
  float mrun[2] = {-3e38f, -3e38f};
  float lrun[2] = {0.f, 0.f};

  const int nsteps = (q0 + 128) >> 5;
  for (int kt = 0; kt < nsteps; kt++) {
    const int kv0 = kt << 5;
    {
      int r = tid >> 3, cc = tid & 7;
      int col8 = (cc ^ (r & 7)) << 3;
      gl_lds16(Kg + (size_t)(kv0 + r)*DH + col8, Ks + ((size_t)(tid & ~63) << 3));
    }
    {
      int d = tid >> 2, cc = tid & 3;
      int col8 = (cc ^ (d & 3)) << 3;
      gl_lds16(Vg + (size_t)d*NN + kv0 + col8, Vs + ((size_t)(tid & ~63) << 3));
    }
    __syncthreads();
    if (kv0 <= wq0 + 31) {
      bf16x8 ka[2][2];
#pragma unroll
      for (int kvf = 0; kvf < 2; kvf++)
#pragma unroll
        for (int c = 0; c < 2; c++) {
          int r = kvf*16 + l15;
          int x = (64*c + 16*h4) ^ (16*(r & 7));
          ka[kvf][c] = *(const bf16x8*)((const char*)Ks + r*128 + x);
        }
      f32x4 st[2][2];
#pragma unroll
      for (int kvf = 0; kvf < 2; kvf++)
#pragma unroll
        for (int qf = 0; qf < 2; qf++) {
          f32x4 s = __builtin_amdgcn_mfma_f32_16x16x32_bf16(ka[kvf][0], qfr[qf][0], zf, 0, 0, 0);
          s = __builtin_amdgcn_mfma_f32_16x16x32_bf16(ka[kvf][1], qfr[qf][1], s, 0, 0, 0);
          st[kvf][qf] = s;
        }
      if (kv0 + 31 > wq0) {
#pragma unroll
        for (int kvf = 0; kvf < 2; kvf++)
#pragma unroll
          for (int j = 0; j < 4; j++) {
            int kvg = kv0 + kvf*16 + h4*4 + j;
#pragma unroll
            for (int qf = 0; qf < 2; qf++) {
              int qg = wq0 + qf*16 + l15;
              if (kvg > qg) st[kvf][qf][j] = -3e38f;
            }
          }
      }
      bf16x8 pa[2];
#pragma unroll
      for (int qf = 0; qf < 2; qf++) {
        float vmax = -3e38f;
#pragma unroll
        for (int kvf = 0; kvf < 2; kvf++)
#pragma unroll
          for (int j = 0; j < 4; j++) vmax = fmaxf(vmax, st[kvf][qf][j]);
        vmax = fmaxf(vmax, __shfl_xor(vmax, 16));
        vmax = fmaxf(vmax, __shfl_xor(vmax, 32));
        float mnew = fmaxf(mrun[qf], vmax);
        float corr = __expf(mrun[qf] - mnew);
        float ps = 0.f;
        float pv_[8];
#pragma unroll
        for (int kvf = 0; kvf < 2; kvf++)
#pragma unroll
          for (int j = 0; j < 4; j++) {
            float p = __expf(st[kvf][qf][j] - mnew);
            pv_[kvf*4 + j] = p; ps += p;
          }
        ps += __shfl_xor(ps, 16);
        ps += __shfl_xor(ps, 32);
        lrun[qf] = lrun[qf]*corr + ps;
        mrun[qf] = mnew;
        bf16x8 t;
#pragma unroll
        for (int i = 0; i < 8; i++) t[i] = (bf16)pv_[i];
        pa[qf] = t;
#pragma unroll
        for (int j = 0; j < 4; j++) {
          float cj = __shfl(corr, (l & 48) | (h4*4 + j), 64);
#pragma unroll
          for (int nf = 0; nf < 4; nf++) o_[qf][nf][j] *= cj;
        }
      }
#pragma unroll
      for (int nf = 0; nf < 4; nf++) {
        int d_ = nf*16 + l15;
        int swz = 16*(d_ & 3);
        const char* vrow = (const char*)Vs + d_*64;
        bf16x4 v0 = *(const bf16x4*)(vrow + ((8*h4) ^ swz));
        bf16x4 v1 = *(const bf16x4*)(vrow + ((8*h4 + 32) ^ swz));
        bf16x8 vb = __builtin_shufflevector(v0, v1, 0,1,2,3,4,5,6,7);
#pragma unroll
        for (int qf = 0; qf < 2; qf++)
          o_[qf][nf] = __builtin_amdgcn_mfma_f32_16x16x32_bf16(pa[qf], vb, o_[qf][nf], 0, 0, 0);
      }
    }
    __syncthreads();
  }
#pragma unroll
  for (int qf = 0; qf < 2; qf++) {
    float inv = 1.f / lrun[qf];
#pragma unroll
    for (int j = 0; j < 4; j++) {
      float ij = __shfl(inv, (l & 48) | (h4*4 + j), 64);
      int qg = wq0 + qf*16 + h4*4 + j;
      size_t rowoff = (size_t)(b*NN + qg) * DIMD + h*DH;
#pragma unroll
      for (int nf = 0; nf < 4; nf++)
        uo[rowoff + nf*16 + l15] = (bf16)(o_[qf][nf][j] * ij);
    }
  }
}

// ---------------- SiLU gating, in-place over ff_x half of proj_ff ----------------
__global__ void k_silu(bf16* __restrict__ pf) {
  const long total4 = (long)MROWS * FFI / 4;
  long stride = (long)gridDim.x * blockDim.x;
  for (long i = (long)blockIdx.x * blockDim.x + threadIdx.x; i < total4; i += stride) {
    long e = i << 2;
    long m = e >> 13;
    int  c = (int)(e & (FFI - 1));
    bf16* px = pf + (m << 14) + c;
    bf16x4 fx = *(const bf16x4*)px;
    bf16x4 gt = *(const bf16x4*)(px + FFI);
    bf16x4 r;
#pragma unroll
    for (int k = 0; k < 4; k++) {
      float g = (float)gt[k], f = (float)fx[k];
      float s = g * (1.f / (1.f + __expf(-g)));
      r[k] = (bf16)(s * f);
    }
    *(bf16x4*)px = r;
  }
}

extern "C" void kernel_launch(void* const* d_in, const int* in_sizes, int n_in,
                              void* d_out, int out_size, void* d_ws, size_t ws_size,
                              hipStream_t stream) {
  const float* x     = (const float*)d_in[0];
  const float* gamma = (const float*)d_in[1];
  const float* Wf    = (const float*)d_in[2];
  const float* Wao   = (const float*)d_in[3];
  const float* Wff   = (const float*)d_in[4];
  float* out = (float*)d_out;
  char* ws = (char*)d_ws;

  size_t o = 0;
  bf16* wfb     = (bf16*)(ws + o); o += (size_t)FUSEDP * DIMD * 2;   // 76.5 MB (padded)
  bf16* wcat    = wfb;                                               // aliased after GEMM1
  bf16* xn      = (bf16*)(ws + o); o += (size_t)MROWS * DIMD * 2;
  bf16* q_raw   = (bf16*)(ws + o); o += (size_t)BB*HEADS*NN*DH * 2;
  bf16* k_buf   = (bf16*)(ws + o); o += (size_t)BB*NN*DH * 2;
  bf16* v_t     = (bf16*)(ws + o); o += (size_t)BB*DH*NN * 2;
  bf16* proj_ff = (bf16*)(ws + o); o += (size_t)MROWS * 2*FFI * 2;
  bf16* u_o     = (bf16*)(ws + o); o += (size_t)MROWS * DIMD * 2;

  k_cvt_str<<<2048, 256, 0, stream>>>(Wf, wfb, (long)FUSEDN*DIMD/4, DIMD, DIMD, 0);
  k_ln<<<MROWS, 256, 0, stream>>>(x, gamma, xn);
  k_gemm1<<<(FUSEDP/256)*(MROWS/256), 512, 0, stream>>>(xn, wfb, q_raw, k_buf, v_t, proj_ff);
  k_cvt_str<<<512,  256, 0, stream>>>(Wao, wcat, (long)DIMD*DIMD/4, DIMD, K2, 0);
  k_cvt_str<<<1024, 256, 0, stream>>>(Wff, wcat, (long)DIMD*FFI/4,  FFI,  K2, DIMD);
  {
    long tot = (long)BB*HEADS*NN*32 + (long)BB*NN*32;
    k_rope<<<(int)((tot + 255) / 256), 256, 0, stream>>>(q_raw, k_buf);
  }
  k_attn<<<BB*HEADS*(NN/128), 256, 0, stream>>>(q_raw, k_buf, v_t, u_o);
  k_silu<<<2048, 256, 0, stream>>>(proj_ff);
  k_gemm2<<<(MROWS/128)*(DIMD/256), 512, 0, stream>>>(u_o, proj_ff, wcat, out);
}